// Round 4
// baseline (294.074 us; speedup 1.0000x reference)
//
#include <hip/hip_runtime.h>

typedef __attribute__((ext_vector_type(8))) short short8;   // 8 x bf16 (4 VGPR)
typedef __attribute__((ext_vector_type(4))) float f32x4;
typedef __attribute__((ext_vector_type(4))) unsigned u32x4;

#define Bsz 4
#define Cin 256
#define Cout 256
#define Hh 64
#define Ww 64
#define HW 4096
#define NG 16
#define EPSV 1e-5f

#define SPAN 16        // staged input rows per plane (covers |dy| <= ~6.5)
// plane c base (floats) = c*1024 + (c>>3)*4  -> quad groups 4 banks apart
#define PGRP 8196      // float stride between quad groups (8*1024 + 4)
#define RSTR 68        // epilogue transpose row stride (floats)

// ---- dynamic LDS layout (bytes) ----
#define OFF_IN   0
#define SZ_IN    131120                // 32 planes x 16 rows x 64 f32 (+pads)
#define OFF_TA   131120                // int2 per tap [9][64]
#define OFF_TW   135728                // float4 per tap [9][64]
#define OFF_CTL  144944                // ymin/ymax
#define SMEM_BYTES 144960

static __device__ __forceinline__ unsigned f2bf(float f) {
    unsigned u = __float_as_uint(f);
    return (u + 0x7fffu + ((u >> 16) & 1u)) >> 16;   // RNE bf16
}

static __device__ __forceinline__ float2 ld8(const float* p) {
    float2 v;
    __builtin_memcpy(&v, p, 8);   // 4B-aligned pair load (global or LDS)
    return v;
}

// ---------------------------------------------------------------------------
// Kernel 1: weight reorder w[o][c][kk] -> bf16 wtb[ks][o][32],  ks = kk*8 + c/32
// Thread = OUTPUT element: coalesced 2B stores; strided reads hit L2.
// Also zeroes the GN stats accumulators.
// ---------------------------------------------------------------------------
__global__ void wt_kernel(const float* __restrict__ w, ushort* __restrict__ wtb,
                          float* __restrict__ stats) {
    const int i = blockIdx.x * 256 + threadIdx.x;      // over 72*256*32 = 589824
    if (blockIdx.x == 0 && threadIdx.x < 128) stats[threadIdx.x] = 0.f;
    if (i >= 72 * 256 * 32) return;
    const int cl = i & 31;                             // c % 32
    const int o  = (i >> 5) & 255;                     // output channel
    const int ks = i >> 13;                            // K-step 0..71
    const int c  = ((ks & 7) << 5) | cl;
    const int kk = ks >> 3;
    wtb[i] = (ushort)f2bf(w[((size_t)o * Cin + c) * 9 + kk]);
}

// ---------------------------------------------------------------------------
// Kernel 2: fused deformable sampling + bf16 MFMA conv + GN partial stats.
// CHANGE vs prev (structural: per-step barrier lockstep was the bottleneck):
// MFMA operands SWAPPED: samples = A-operand (lane l15 = pixel, quad = k-slice
// -> fragment produced fully in-lane by the gather, NO LDS exchange, NO
// per-step barrier); weights = B-operand (coalesced 1KB loads, L2-resident).
// Wave tile: 16 px (pg=wv&3) x 128 Co (oh=wv>>2); 8 waves independent within
// each 32-ch chunk; barriers only at chunk re-staging (16 total vs 72).
// Epilogue: stats from regs; LDS transpose (reusing s_in) for coalesced store.
// ---------------------------------------------------------------------------
__launch_bounds__(512, 1)
__global__ void dcn_kernel(const float* __restrict__ in,
                           const float* __restrict__ offs,
                           const float* __restrict__ mask,
                           const ushort* __restrict__ wtb,
                           const float* __restrict__ bias,
                           float* __restrict__ out,
                           float* __restrict__ stats) {
    extern __shared__ char smem[];
    float*  s_in = (float*)(smem + OFF_IN);     // 32 planes, padded
    int2*   s_ta = (int2*)(smem + OFF_TA);      // [576]
    float4* s_tw = (float4*)(smem + OFF_TW);    // [576]
    int*    s_ctl = (int*)(smem + OFF_CTL);     // [0]=ymin [1]=ymax

    const int t  = threadIdx.x;
    const int bx = blockIdx.x;
    // XCD swizzle: XCD q = bx&7 serves batch q>>1, h-half q&1 (L2 locality)
    const int q  = bx & 7, r = bx >> 3;
    const int b  = q >> 1;
    const int h  = ((q & 1) << 5) | r;
    const int lane = t & 63;
    const int wv   = t >> 6;               // wave 0..7
    const int quad = lane >> 4;
    const int l15  = lane & 15;
    const int pg   = wv & 3;               // pixel group: px = pg*16 + l15
    const int oh   = wv >> 2;              // o-half: o = oh*128 + og*16 + l15
    const int myp  = pg * 16 + l15;        // this lane's pixel (A-frag row)

    if (t < 2) s_ctl[t] = (t == 0) ? 64 : -1;
    __syncthreads();

    // ---- tap precompute: 9 kernel points x 64 pixels, + block row min/max ----
    int my_min = 64, my_max = -1;
    for (int j = t; j < 576; j += 512) {
        const int k = j >> 6, pp = j & 63;
        const float* ob = offs + (size_t)b * 18 * HW + h * Ww + pp;
        const float dy = ob[(2 * k) * HW];
        const float dx = ob[(2 * k + 1) * HW];
        const float m  = mask[((size_t)b * 9 + k) * HW + h * Ww + pp];
        const float y = (float)h + (float)(k / 3 - 1) + dy;
        const float x = (float)pp + (float)(k % 3 - 1) + dx;
        const float y0f = floorf(y), x0f = floorf(x);
        const float ly = y - y0f, lx = x - x0f;
        const float hy = 1.f - ly, hx = 1.f - lx;
        const int y0 = (int)y0f, x0 = (int)x0f;
        const int yc0 = min(max(y0, 0), 63);
        const int yc1 = min(max(y0 + 1, 0), 63);
        const int xb  = min(max(x0, 0), 62);
        // col-remapped pair coefficients (corner validity folded):
        //   v.x = row[xb], v.y = row[xb+1]
        float ax = 0.f, ay = 0.f;
        if (x0 == xb) {                       // x0 in [0,62]: both corners in-row
            ax = hx;
            ay = lx;
        } else if (x0 < xb) {                 // x0 < 0
            ax = (x0 + 1 == 0) ? lx : 0.f;
        } else {                              // x0 > 62
            ay = (x0 == 63) ? hx : 0.f;
        }
        const float w0 = (y0 >= 0 && y0 < 64) ? m * hy : 0.f;
        const float w1 = (y0 + 1 >= 0 && y0 + 1 < 64) ? m * ly : 0.f;
        s_ta[j] = make_int2(yc0 * 64 + xb, yc1 * 64 + xb);
        s_tw[j] = make_float4(w0 * ax, w0 * ay, w1 * ax, w1 * ay);
        my_min = min(my_min, yc0);
        my_max = max(my_max, yc1);
    }
#pragma unroll
    for (int off = 32; off; off >>= 1) {
        my_min = min(my_min, __shfl_xor(my_min, off));
        my_max = max(my_max, __shfl_xor(my_max, off));
    }
    if (lane == 0) {
        atomicMin(&s_ctl[0], my_min);
        atomicMax(&s_ctl[1], my_max);
    }
    __syncthreads();

    const int ymin = s_ctl[0];
    const bool use_lds = (s_ctl[1] - ymin + 1) <= SPAN;
    const int ymin64 = ymin << 6;

    f32x4 acc[8];
#pragma unroll
    for (int og = 0; og < 8; og++) acc[og] = (f32x4){0.f, 0.f, 0.f, 0.f};

    const float* inb = in + (size_t)b * Cin * HW;

    // Stage chunk cc's 32 planes x SPAN rows into LDS via async global->LDS.
    // 128 segments of 1KB; +16B pad every 8 planes (keeps quad-lanes on
    // distinct banks during the gather). Dest = wave-uniform base + lane*16.
#define STAGE(cc)                                                              \
    {                                                                          \
        const float* cbs = inb + (size_t)((cc) * 32) * HW;                     \
        _Pragma("unroll")                                                      \
        for (int i = 0; i < 16; i++) {                                         \
            const int g = (wv << 4) | i;                                       \
            const int plane = g >> 2;                                          \
            const int row = min(ymin + ((g & 3) << 2) + (lane >> 4), 63);      \
            const float* src = cbs + (size_t)plane * HW + row * 64 +           \
                               ((lane & 15) << 2);                             \
            __builtin_amdgcn_global_load_lds(                                  \
                (const __attribute__((address_space(1))) void*)src,            \
                (__attribute__((address_space(3))) void*)(smem +               \
                    (plane * 4096 + ((plane >> 3) << 4) + ((g & 3) << 10))),   \
                16, 0, 0);                                                     \
        }                                                                      \
    }

    if (use_lds) {
        STAGE(0);
        __syncthreads();                 // drains vmcnt: chunk 0 staged
#pragma unroll 1
        for (int cc = 0; cc < 8; cc++) {
#pragma unroll
            for (int kk = 0; kk < 9; kk++) {
                const int ks = kk * 8 + cc;
                // ---- B-frags: weights, coalesced 1KB/instr, L2-resident ----
                const ushort* wp =
                    wtb + ((size_t)(ks * 256 + oh * 128 + l15)) * 32 + quad * 8;
                short8 bf[8];
#pragma unroll
                for (int og = 0; og < 8; og++)
                    bf[og] = *(const short8*)(wp + og * 512);
                // ---- A-frag: gather 8 channels of my pixel from LDS ----
                const int2  ad = s_ta[kk * 64 + myp];
                const float4 tw = s_tw[kk * 64 + myp];
                const int r0 = ad.x - ymin64, r1 = ad.y - ymin64;
                const float* cb = s_in + quad * PGRP;
                u32x4 apk;
#pragma unroll
                for (int jj = 0; jj < 4; jj++) {
                    const float* p0 = cb + jj * 2048;
                    const float* p1 = p0 + 1024;
                    const float2 g0 = ld8(p0 + r0);
                    const float2 g1 = ld8(p0 + r1);
                    const float2 h0 = ld8(p1 + r0);
                    const float2 h1 = ld8(p1 + r1);
                    const float va = tw.x * g0.x + tw.y * g0.y +
                                     tw.z * g1.x + tw.w * g1.y;
                    const float vb = tw.x * h0.x + tw.y * h0.y +
                                     tw.z * h1.x + tw.w * h1.y;
                    apk[jj] = f2bf(va) | (f2bf(vb) << 16);
                }
                const short8 af = __builtin_bit_cast(short8, apk);
#pragma unroll
                for (int og = 0; og < 8; og++)
                    acc[og] = __builtin_amdgcn_mfma_f32_16x16x32_bf16(
                        af, bf[og], acc[og], 0, 0, 0);
            }
            __syncthreads();             // all waves done gathering chunk cc
            if (cc < 7) {
                STAGE(cc + 1);
                __syncthreads();         // staging complete (vmcnt drained)
            }
        }
    } else {
        // fallback: gather straight from global (span > SPAN; ~never taken)
#pragma unroll 1
        for (int cc = 0; cc < 8; cc++) {
#pragma unroll 1
            for (int kk = 0; kk < 9; kk++) {
                const int ks = kk * 8 + cc;
                const ushort* wp =
                    wtb + ((size_t)(ks * 256 + oh * 128 + l15)) * 32 + quad * 8;
                short8 bf[8];
#pragma unroll
                for (int og = 0; og < 8; og++)
                    bf[og] = *(const short8*)(wp + og * 512);
                const int2  ad = s_ta[kk * 64 + myp];
                const float4 tw = s_tw[kk * 64 + myp];
                const float* cbq = inb + (size_t)(cc * 32 + quad * 8) * HW;
                u32x4 apk;
#pragma unroll
                for (int jj = 0; jj < 4; jj++) {
                    const float* p0 = cbq + (size_t)(2 * jj) * HW;
                    const float* p1 = p0 + HW;
                    const float2 g0 = ld8(p0 + ad.x);
                    const float2 g1 = ld8(p0 + ad.y);
                    const float2 h0 = ld8(p1 + ad.x);
                    const float2 h1 = ld8(p1 + ad.y);
                    const float va = tw.x * g0.x + tw.y * g0.y +
                                     tw.z * g1.x + tw.w * g1.y;
                    const float vb = tw.x * h0.x + tw.y * h0.y +
                                     tw.z * h1.x + tw.w * h1.y;
                    apk[jj] = f2bf(va) | (f2bf(vb) << 16);
                }
                const short8 af = __builtin_bit_cast(short8, apk);
#pragma unroll
                for (int og = 0; og < 8; og++)
                    acc[og] = __builtin_amdgcn_mfma_f32_16x16x32_bf16(
                        af, bf[og], acc[og], 0, 0, 0);
            }
        }
    }
#undef STAGE

    // ---- epilogue: bias + GN partial stats straight from registers ----
    // C mapping: col(lane&15) = o-within-group, row(quad*4+reg) = px-within-pg
    const int obase = oh * 128 + l15;
#pragma unroll
    for (int og = 0; og < 8; og++) {
        const float bv = bias[obase + og * 16];
        float s = 0.f, qq = 0.f;
#pragma unroll
        for (int reg = 0; reg < 4; reg++) {
            acc[og][reg] += bv;
            s += acc[og][reg];
            qq += acc[og][reg] * acc[og][reg];
        }
#pragma unroll
        for (int off = 32; off; off >>= 1) {
            s  += __shfl_xor(s, off);
            qq += __shfl_xor(qq, off);
        }
        if (lane == 0) {
            const int g = oh * 8 + og;       // all lanes of this og: one group
            atomicAdd(&stats[((size_t)b * NG + g) * 2],     s);
            atomicAdd(&stats[((size_t)b * NG + g) * 2 + 1], qq);
        }
    }

    // ---- transpose via LDS (reuse s_in) for coalesced global stores ----
    __syncthreads();                     // everyone done reading s_in
    float* red = s_in;                   // red[o][px], row stride RSTR
#pragma unroll
    for (int og = 0; og < 8; og++)
        *(f32x4*)&red[(size_t)(obase + og * 16) * RSTR + pg * 16 + (quad << 2)] =
            acc[og];
    __syncthreads();
    const f32x4* redv = (const f32x4*)red;   // row stride 17 f32x4
    float* outb = out + (size_t)b * Cout * HW + h * Ww;
#pragma unroll
    for (int rr = 0; rr < 8; rr++) {
        const int idx = t + rr * 512;        // 4096 float4s = 256 o x 16
        const int o = idx >> 4, x4 = idx & 15;
        *(f32x4*)(outb + (size_t)o * HW + x4 * 4) = redv[o * 17 + x4];
    }
}

// ---------------------------------------------------------------------------
// Kernel 3: GN apply (mu/rsqrt from accumulated sums, in place)
// ---------------------------------------------------------------------------
__global__ void gn_apply_kernel(float* __restrict__ x, const float* __restrict__ stats,
                                const float* __restrict__ gamma,
                                const float* __restrict__ beta) {
    const int i = blockIdx.x * 256 + threadIdx.x;      // float4 idx, 1048576 total
    const int plane = i >> 10;                         // b*256 + o
    const int o = plane & 255;
    const int bg = plane >> 4;                         // b*16 + g
    const float s = stats[bg * 2], q = stats[bg * 2 + 1];
    const float inv_n = 1.f / 65536.f;
    const float mu = s * inv_n;
    const float var = q * inv_n - mu * mu;
    const float rs = rsqrtf(var + EPSV);
    const float ga = gamma[o] * rs;
    const float be = beta[o] - mu * ga;
    float4 v = ((float4*)x)[i];
    v.x = v.x * ga + be;
    v.y = v.y * ga + be;
    v.z = v.z * ga + be;
    v.w = v.w * ga + be;
    ((float4*)x)[i] = v;
}

// ---------------------------------------------------------------------------
extern "C" void kernel_launch(void* const* d_in, const int* in_sizes, int n_in,
                              void* d_out, int out_size, void* d_ws, size_t ws_size,
                              hipStream_t stream) {
    const float* input  = (const float*)d_in[0];
    const float* offset = (const float*)d_in[1];
    const float* maskp  = (const float*)d_in[2];
    const float* weight = (const float*)d_in[3];
    const float* bias   = (const float*)d_in[4];
    const float* gamma  = (const float*)d_in[5];
    const float* beta   = (const float*)d_in[6];
    float* out = (float*)d_out;

    ushort* wtb  = (ushort*)d_ws;                           // 1.18 MB
    float* stats = (float*)((char*)d_ws + (size_t)Cout * Cin * 9 * sizeof(ushort));

    static int attr_done = 0;
    if (!attr_done) {
        hipFuncSetAttribute((const void*)dcn_kernel,
                            hipFuncAttributeMaxDynamicSharedMemorySize, SMEM_BYTES);
        attr_done = 1;
    }

    hipLaunchKernelGGL(wt_kernel, dim3((Cout * Cin * 9 + 255) / 256), dim3(256), 0,
                       stream, weight, wtb, stats);
    hipLaunchKernelGGL(dcn_kernel, dim3(Bsz * Hh), dim3(512), SMEM_BYTES, stream,
                       input, offset, maskp, wtb, bias, out, stats);
    hipLaunchKernelGGL(gn_apply_kernel, dim3((Bsz * Cout * HW / 4) / 256), dim3(256), 0,
                       stream, out, stats, gamma, beta);
}

// Round 5
// 194.429 us; speedup vs baseline: 1.5125x; 1.5125x over previous
//
#include <hip/hip_runtime.h>

typedef __attribute__((ext_vector_type(8))) short short8;   // 8 x bf16 (4 VGPR)
typedef __attribute__((ext_vector_type(4))) float f32x4;
typedef __attribute__((ext_vector_type(4))) unsigned u32x4;

#define Bsz 4
#define Cin 256
#define Cout 256
#define Hh 64
#define Ww 64
#define HW 4096
#define NG 16
#define EPSV 1e-5f

#define CSTR 40        // col LDS row stride in ushorts: 32 data + 8 pad = 80 B
#define SPAN 12        // staged input rows per plane window
#define ROWB 4112      // staged row stride bytes: 4 cs x 64 px x 16B + 16 pad

// ---- dcn dynamic LDS layout (bytes) ----
#define OFF_IN   0
#define SZ_IN    (SPAN * ROWB)         // 49344: bf16 NHWC-interleaved window
#define OFF_COL  49344                 // 2 x 64 x CSTR ushorts (dbuf col tile)
#define OFF_TA   59584                 // int2 per tap [9][64]
#define OFF_TW   64192                 // float4 per tap [9][64]
#define OFF_CTL  73408                 // ymin/ymax
#define SMEM_BYTES 73424               // x2 blocks = 146848 <= 160 KiB/CU

static __device__ __forceinline__ unsigned f2bf(float f) {
    unsigned u = __float_as_uint(f);
    return (u + 0x7fffu + ((u >> 16) & 1u)) >> 16;   // RNE bf16
}

static __device__ __forceinline__ float2 ld8(const float* p) {
    float2 v;
    __builtin_memcpy(&v, p, 8);   // 8B load (global or LDS)
    return v;
}

#define BLO(u) __uint_as_float((u) << 16)          // bf16 in low half -> f32
#define BHI(u) __uint_as_float((u) & 0xffff0000u)  // bf16 in high half -> f32

// ---------------------------------------------------------------------------
// Kernel 1: weight reorder w[o][c][kk] -> bf16 wtb[ks][o][32],  ks = kk*8 + c/32
// Thread = OUTPUT element: coalesced 2B stores; strided reads hit L2.
// Also zeroes the GN stats accumulators.
// ---------------------------------------------------------------------------
__global__ void wt_kernel(const float* __restrict__ w, ushort* __restrict__ wtb,
                          float* __restrict__ stats) {
    const int i = blockIdx.x * 256 + threadIdx.x;      // over 72*256*32 = 589824
    if (blockIdx.x == 0 && threadIdx.x < 128) stats[threadIdx.x] = 0.f;
    if (i >= 72 * 256 * 32) return;
    const int cl = i & 31;                             // c % 32
    const int o  = (i >> 5) & 255;                     // output channel
    const int ks = i >> 13;                            // K-step 0..71
    const int c  = ((ks & 7) << 5) | cl;
    const int kk = ks >> 3;
    wtb[i] = (ushort)f2bf(w[((size_t)o * Cin + c) * 9 + kk]);
}

// ---------------------------------------------------------------------------
// Kernel 1b: input transpose NCHW f32 -> interleaved bf16
//   inT unit(16B = 8ch) index = ((b*64 + y)*32 + cs)*64 + x,  cs = c>>3
// Block = (b, h, chalf): 512 thr; LDS 128x68 f32 tile transpose.
// ---------------------------------------------------------------------------
__global__ void tr_kernel(const float* __restrict__ in, ushort* __restrict__ inT) {
    __shared__ float s_t[128 * 68];                    // 34816 B
    const int t  = threadIdx.x;
    const int bx = blockIdx.x;                         // b*128 + h*2 + chalf
    const int b  = bx >> 7;
    const int h  = (bx >> 1) & 63;
    const int ch = bx & 1;
    const float* src = in + ((size_t)(b * 256 + ch * 128)) * HW + h * 64;
#pragma unroll
    for (int j = 0; j < 4; j++) {
        const int fi = t + j * 512;                    // float4 idx over 2048
        const int lc = fi >> 4, x4 = fi & 15;
        *(f32x4*)&s_t[lc * 68 + x4 * 4] =
            *(const f32x4*)(src + (size_t)lc * HW + x4 * 4);
    }
    __syncthreads();
    ushort* dstb = inT + ((size_t)(b * 64 + h) * 32 + ch * 16) * 512;
#pragma unroll
    for (int j = 0; j < 2; j++) {
        const int u = t + j * 512;                     // 0..1023: csl*64 + x
        const int csl = u >> 6, x = u & 63;
        const float* sp = &s_t[(csl * 8) * 68 + x];
        u32x4 d;
#pragma unroll
        for (int i = 0; i < 4; i++)
            d[i] = f2bf(sp[(2 * i) * 68]) | (f2bf(sp[(2 * i + 1) * 68]) << 16);
        *(u32x4*)(dstb + (size_t)u * 8) = d;
    }
}

// ---------------------------------------------------------------------------
// Kernel 2: fused deformable sampling + bf16 MFMA conv + GN partial stats.
// Round-2 skeleton (byte-optimal col-exchange pipeline) with:
//  - bf16 NHWC-interleaved LDS window: gather = 4 x ld8 per thread per step
//    (halved probes+bytes), ~2-way banks (pixel stride 16B, row-jitter pad).
//  - SPAN 12 bf16 window -> 73.4 KB LDS -> 2 blocks/CU (latency overlap).
// Block: 512 threads (8 waves) = one image row (b,h): N=64 px, M=256 Co.
// ---------------------------------------------------------------------------
__launch_bounds__(512, 4)
__global__ void dcn_kernel(const float* __restrict__ in,
                           const ushort* __restrict__ inT,
                           const float* __restrict__ offs,
                           const float* __restrict__ mask,
                           const ushort* __restrict__ wtb,
                           const float* __restrict__ bias,
                           float* __restrict__ out,
                           float* __restrict__ stats) {
    extern __shared__ char smem[];
    ushort* col  = (ushort*)(smem + OFF_COL);   // [2][64*CSTR]
    int2*   s_ta = (int2*)(smem + OFF_TA);      // [576]
    float4* s_tw = (float4*)(smem + OFF_TW);    // [576]
    int*    s_ctl = (int*)(smem + OFF_CTL);     // [0]=ymin [1]=ymax

    const int t  = threadIdx.x;
    const int bx = blockIdx.x;
    // XCD swizzle: XCD q = bx&7 serves batch q>>1, h-half q&1 (L2 locality)
    const int q  = bx & 7, r = bx >> 3;
    const int b  = q >> 1;
    const int h  = ((q & 1) << 5) | r;
    const int lane = t & 63;
    const int wv   = t >> 6;               // wave 0..7
    const int n    = lane;                 // pixel in row
    const int quad = lane >> 4;
    const int l15  = lane & 15;
    // gather channel mapping: c = wv*4..+3  ->  cs = wv>>1, half = wv&1
    const int csoff = (wv >> 1) * 1024 + (wv & 1) * 8;   // thread-const byte off

    if (t < 2) s_ctl[t] = (t == 0) ? 64 : -1;
    __syncthreads();

    // ---- tap precompute: 9 kernel points x 64 pixels, + block row min/max ----
    int my_min = 64, my_max = -1;
    for (int j = t; j < 576; j += 512) {
        const int k = j >> 6, pp = j & 63;
        const float* ob = offs + (size_t)b * 18 * HW + h * Ww + pp;
        const float dy = ob[(2 * k) * HW];
        const float dx = ob[(2 * k + 1) * HW];
        const float m  = mask[((size_t)b * 9 + k) * HW + h * Ww + pp];
        const float y = (float)h + (float)(k / 3 - 1) + dy;
        const float x = (float)pp + (float)(k % 3 - 1) + dx;
        const float y0f = floorf(y), x0f = floorf(x);
        const float ly = y - y0f, lx = x - x0f;
        const float hy = 1.f - ly, hx = 1.f - lx;
        const int y0 = (int)y0f, x0 = (int)x0f;
        const int yc0 = min(max(y0, 0), 63);
        const int yc1 = min(max(y0 + 1, 0), 63);
        const int xb  = min(max(x0, 0), 62);
        // col-remapped pair coefficients (corner validity folded):
        //   v.x = col[xb], v.y = col[xb+1]
        float ax = 0.f, ay = 0.f;
        if (x0 == xb) {                       // x0 in [0,62]: both corners in-row
            ax = hx;
            ay = lx;
        } else if (x0 < xb) {                 // x0 < 0
            ax = (x0 + 1 == 0) ? lx : 0.f;
        } else {                              // x0 > 62
            ay = (x0 == 63) ? hx : 0.f;
        }
        const float w0 = (y0 >= 0 && y0 < 64) ? m * hy : 0.f;
        const float w1 = (y0 + 1 >= 0 && y0 + 1 < 64) ? m * ly : 0.f;
        // ta in staged-LDS byte units: row*ROWB + x*16
        s_ta[j] = make_int2(yc0 * ROWB + xb * 16, yc1 * ROWB + xb * 16);
        s_tw[j] = make_float4(w0 * ax, w0 * ay, w1 * ax, w1 * ay);
        my_min = min(my_min, yc0);
        my_max = max(my_max, yc1);
    }
#pragma unroll
    for (int off = 32; off; off >>= 1) {
        my_min = min(my_min, __shfl_xor(my_min, off));
        my_max = max(my_max, __shfl_xor(my_max, off));
    }
    if (lane == 0) {
        atomicMin(&s_ctl[0], my_min);
        atomicMax(&s_ctl[1], my_max);
    }
    __syncthreads();

    const int ymin = s_ctl[0];
    const bool use_lds = (s_ctl[1] - ymin + 1) <= SPAN;
    const int ybase = ymin * ROWB;

    f32x4 acc[2][4];
#pragma unroll
    for (int i = 0; i < 2; i++)
#pragma unroll
        for (int nt = 0; nt < 4; nt++) acc[i][nt] = (f32x4){0.f, 0.f, 0.f, 0.f};

    const float* inb = in + (size_t)b * Cin * HW;

    // Stage chunk cc's window: SPAN rows x 4 cslots x 64 px x 16B = 48 KB.
    // 48 linear 1KB segments (global contiguous, LDS dest = base + lane*16).
#define STAGE(cc)                                                              \
    {                                                                          \
        _Pragma("unroll")                                                      \
        for (int i = 0; i < 6; i++) {                                          \
            const int g = wv * 6 + i;                                          \
            const int rr = g >> 2, csl = g & 3;                                \
            const int row = min(ymin + rr, 63);                                \
            const ushort* src = inT +                                          \
                (((size_t)(b * 64 + row) * 32 + (cc) * 4 + csl) * 64 + lane) * 8; \
            __builtin_amdgcn_global_load_lds(                                  \
                (const __attribute__((address_space(1))) void*)src,            \
                (__attribute__((address_space(3))) void*)(smem + OFF_IN +      \
                    rr * ROWB + csl * 1024),                                   \
                16, 0, 0);                                                     \
        }                                                                      \
    }

    // gather 4 bf16 channels (one 8B unit per corner) from the staged window
#define GATHER_L(kk, pk0, pk1)                                             \
    {                                                                      \
        const int2  ad = s_ta[(kk) * 64 + n];                              \
        const float4 tw = s_tw[(kk) * 64 + n];                             \
        const char* bp = smem + OFF_IN + csoff - ybase;                    \
        const float2 f00 = ld8((const float*)(bp + ad.x));                 \
        const float2 f01 = ld8((const float*)(bp + ad.x + 16));            \
        const float2 f10 = ld8((const float*)(bp + ad.y));                 \
        const float2 f11 = ld8((const float*)(bp + ad.y + 16));            \
        const unsigned u00x = __float_as_uint(f00.x), u00y = __float_as_uint(f00.y); \
        const unsigned u01x = __float_as_uint(f01.x), u01y = __float_as_uint(f01.y); \
        const unsigned u10x = __float_as_uint(f10.x), u10y = __float_as_uint(f10.y); \
        const unsigned u11x = __float_as_uint(f11.x), u11y = __float_as_uint(f11.y); \
        const float v0 = tw.x * BLO(u00x) + tw.y * BLO(u01x) +             \
                         tw.z * BLO(u10x) + tw.w * BLO(u11x);              \
        const float v1 = tw.x * BHI(u00x) + tw.y * BHI(u01x) +             \
                         tw.z * BHI(u10x) + tw.w * BHI(u11x);              \
        const float v2 = tw.x * BLO(u00y) + tw.y * BLO(u01y) +             \
                         tw.z * BLO(u10y) + tw.w * BLO(u11y);              \
        const float v3 = tw.x * BHI(u00y) + tw.y * BHI(u01y) +             \
                         tw.z * BHI(u10y) + tw.w * BHI(u11y);              \
        pk0 = f2bf(v0) | (f2bf(v1) << 16);                                 \
        pk1 = f2bf(v2) | (f2bf(v3) << 16);                                 \
    }

    // fallback: gather from NCHW global f32 (span > SPAN; ~never taken).
    // Derives (row, xb) back from the ta byte-offset format.
#define GATHER_G(cc, kk, pk0, pk1)                                         \
    {                                                                      \
        const int2  ad = s_ta[(kk) * 64 + n];                              \
        const float4 tw = s_tw[(kk) * 64 + n];                             \
        const int y0r = ad.x / ROWB, x0r = (ad.x - y0r * ROWB) >> 4;       \
        const int y1r = ad.y / ROWB, x1r = (ad.y - y1r * ROWB) >> 4;       \
        const int adx = y0r * 64 + x0r, ady = y1r * 64 + x1r;              \
        const float* cb = inb + (size_t)((cc) * 32 + wv * 4) * HW;         \
        float vv[4];                                                       \
        _Pragma("unroll")                                                  \
        for (int j = 0; j < 4; j++) {                                      \
            const float* pl = cb + j * HW;                                 \
            const float2 g0 = ld8(pl + adx);                               \
            const float2 g1 = ld8(pl + ady);                               \
            vv[j] = tw.x * g0.x + tw.y * g0.y + tw.z * g1.x + tw.w * g1.y; \
        }                                                                  \
        pk0 = f2bf(vv[0]) | (f2bf(vv[1]) << 16);                           \
        pk1 = f2bf(vv[2]) | (f2bf(vv[3]) << 16);                           \
    }

#define FRAGS_MFMA(ks, p)                                                      \
    {                                                                          \
        const ushort* wp =                                                     \
            wtb + ((size_t)((ks) * 256 + wv * 32 + l15)) * 32 + quad * 8;      \
        const short8 a0 = *(const short8*)wp;                                  \
        const short8 a1 = *(const short8*)(wp + 16 * 32);                      \
        short8 bfr[4];                                                         \
        _Pragma("unroll")                                                      \
        for (int nt = 0; nt < 4; nt++)                                         \
            bfr[nt] = *(const short8*)&col[(p) * (64 * CSTR) +                 \
                                           (nt * 16 + l15) * CSTR + quad * 8]; \
        _Pragma("unroll")                                                      \
        for (int nt = 0; nt < 4; nt++) {                                       \
            acc[0][nt] = __builtin_amdgcn_mfma_f32_16x16x32_bf16(              \
                a0, bfr[nt], acc[0][nt], 0, 0, 0);                             \
            acc[1][nt] = __builtin_amdgcn_mfma_f32_16x16x32_bf16(              \
                a1, bfr[nt], acc[1][nt], 0, 0, 0);                             \
        }                                                                      \
    }

    unsigned pk0, pk1;
    int p = 0;

    if (use_lds) {
        STAGE(0);
        __syncthreads();                 // drains vmcnt: chunk 0 staged
        GATHER_L(0, pk0, pk1);
#pragma unroll 1
        for (int s = 0; s < 72; s++) {
            const int cc = s / 9;
            const int kk = s - cc * 9;
            const int ks = kk * 8 + cc;
            *(unsigned long long*)&col[p * (64 * CSTR) + n * CSTR + (wv << 2)] =
                (unsigned long long)pk0 | ((unsigned long long)pk1 << 32);
            __syncthreads();
            // all gathers of chunk cc done before this barrier -> safe to
            // overwrite the window with chunk cc+1.
            const bool bound = (kk == 8) && (s != 71);
            if (bound) {
                STAGE(cc + 1);           // async loads fly over the MFMAs
            } else if (s != 71) {
                GATHER_L(kk + 1, pk0, pk1);
            }
            FRAGS_MFMA(ks, p);
            if (bound) {
                __syncthreads();         // staging complete (vmcnt drained)
                GATHER_L(0, pk0, pk1);
            }
            p ^= 1;
        }
    } else {
        GATHER_G(0, 0, pk0, pk1);
#pragma unroll 1
        for (int s = 0; s < 72; s++) {
            const int cc = s / 9;
            const int kk = s - cc * 9;
            const int ks = kk * 8 + cc;
            *(unsigned long long*)&col[p * (64 * CSTR) + n * CSTR + (wv << 2)] =
                (unsigned long long)pk0 | ((unsigned long long)pk1 << 32);
            __syncthreads();
            if (s < 71) {
                const int s1 = s + 1;
                const int cc1 = s1 / 9;
                GATHER_G(cc1, s1 - cc1 * 9, pk0, pk1);
            }
            FRAGS_MFMA(ks, p);
            p ^= 1;
        }
    }
#undef STAGE
#undef GATHER_L
#undef GATHER_G
#undef FRAGS_MFMA

    // ---- epilogue: bias, store, GN partial stats ----
    float gs[2], gq[2];
#pragma unroll
    for (int i = 0; i < 2; i++) {
        float s = 0.f, qq = 0.f;
        const int ob = wv * 32 + i * 16 + quad * 4;
#pragma unroll
        for (int reg = 0; reg < 4; reg++) {
            const int o = ob + reg;
            const float bv = bias[o];
            float* op = out + ((size_t)(b * 256 + o)) * HW + h * Ww + l15;
#pragma unroll
            for (int nt = 0; nt < 4; nt++) {
                const float v = acc[i][nt][reg] + bv;
                op[nt * 16] = v;
                s += v;
                qq += v * v;
            }
        }
        gs[i] = s; gq[i] = qq;
    }
#pragma unroll
    for (int off = 32; off; off >>= 1) {
        gs[0] += __shfl_xor(gs[0], off);
        gq[0] += __shfl_xor(gq[0], off);
        gs[1] += __shfl_xor(gs[1], off);
        gq[1] += __shfl_xor(gq[1], off);
    }
    if (lane == 0) {
#pragma unroll
        for (int i = 0; i < 2; i++) {
            const int g = wv * 2 + i;
            atomicAdd(&stats[((size_t)b * NG + g) * 2],     gs[i]);
            atomicAdd(&stats[((size_t)b * NG + g) * 2 + 1], gq[i]);
        }
    }
}

// ---------------------------------------------------------------------------
// Kernel 3: GN apply (mu/rsqrt from accumulated sums, in place)
// ---------------------------------------------------------------------------
__global__ void gn_apply_kernel(float* __restrict__ x, const float* __restrict__ stats,
                                const float* __restrict__ gamma,
                                const float* __restrict__ beta) {
    const int i = blockIdx.x * 256 + threadIdx.x;      // float4 idx, 1048576 total
    const int plane = i >> 10;                         // b*256 + o
    const int o = plane & 255;
    const int bg = plane >> 4;                         // b*16 + g
    const float s = stats[bg * 2], q = stats[bg * 2 + 1];
    const float inv_n = 1.f / 65536.f;
    const float mu = s * inv_n;
    const float var = q * inv_n - mu * mu;
    const float rs = rsqrtf(var + EPSV);
    const float ga = gamma[o] * rs;
    const float be = beta[o] - mu * ga;
    float4 v = ((float4*)x)[i];
    v.x = v.x * ga + be;
    v.y = v.y * ga + be;
    v.z = v.z * ga + be;
    v.w = v.w * ga + be;
    ((float4*)x)[i] = v;
}

// ---------------------------------------------------------------------------
extern "C" void kernel_launch(void* const* d_in, const int* in_sizes, int n_in,
                              void* d_out, int out_size, void* d_ws, size_t ws_size,
                              hipStream_t stream) {
    const float* input  = (const float*)d_in[0];
    const float* offset = (const float*)d_in[1];
    const float* maskp  = (const float*)d_in[2];
    const float* weight = (const float*)d_in[3];
    const float* bias   = (const float*)d_in[4];
    const float* gamma  = (const float*)d_in[5];
    const float* beta   = (const float*)d_in[6];
    float* out = (float*)d_out;

    ushort* wtb  = (ushort*)d_ws;                           // 1.18 MB
    float* stats = (float*)((char*)d_ws + (size_t)Cout * Cin * 9 * sizeof(ushort));
    ushort* inT  = (ushort*)((char*)d_ws + 1180160);        // 8 MB bf16 NHWC-ish

    static int attr_done = 0;
    if (!attr_done) {
        hipFuncSetAttribute((const void*)dcn_kernel,
                            hipFuncAttributeMaxDynamicSharedMemorySize, SMEM_BYTES);
        attr_done = 1;
    }

    hipLaunchKernelGGL(wt_kernel, dim3((Cout * Cin * 9 + 255) / 256), dim3(256), 0,
                       stream, weight, wtb, stats);
    hipLaunchKernelGGL(tr_kernel, dim3(Bsz * Hh * 2), dim3(512), 0,
                       stream, input, inT);
    hipLaunchKernelGGL(dcn_kernel, dim3(Bsz * Hh), dim3(512), SMEM_BYTES, stream,
                       input, inT, offset, maskp, wtb, bias, out, stats);
    hipLaunchKernelGGL(gn_apply_kernel, dim3((Bsz * Cout * HW / 4) / 256), dim3(256), 0,
                       stream, out, stats, gamma, beta);
}